// Round 9
// baseline (233.883 us; speedup 1.0000x reference)
//
#include <hip/hip_runtime.h>
#include <hip/hip_bf16.h>

typedef __attribute__((ext_vector_type(8))) short bf16x8;
typedef __attribute__((ext_vector_type(4))) float f32x4;

__device__ inline short f2bf(float f) {
    __hip_bfloat16 h = __float2bfloat16(f);
    short s;
    __builtin_memcpy(&s, &h, 2);
    return s;
}
__device__ inline float bf2f(short s) {
    unsigned int u = ((unsigned int)(unsigned short)s) << 16;
    float f;
    __builtin_memcpy(&f, &u, 4);
    return f;
}

// async 16B global->LDS; dest must be wave-uniform base + lane*16
__device__ inline void cp16_async(const void* g, void* l) {
    __builtin_amdgcn_global_load_lds(
        (const __attribute__((address_space(1))) void*)g,
        (__attribute__((address_space(3))) void*)l, 16, 0, 0);
}

// ---------------- prep: cast x + LDS-tiled transpose-cast of 4 weights ----------------
__global__ void prep_kernel(const float* __restrict__ x, short* __restrict__ Xb,
                            const float* __restrict__ W0, const float* __restrict__ W1,
                            const float* __restrict__ W2, const float* __restrict__ W3,
                            short* __restrict__ W4T) {
    __shared__ short sT[64][72];   // 144B rows, 16B-aligned
    const int bid = blockIdx.x, tid = threadIdx.x;
    if (bid < 8192) {
        int i = bid * 256 + tid;
        float4 f = ((const float4*)x)[i];
        union { short s[4]; int2 v; } u;
        u.s[0] = f2bf(f.x); u.s[1] = f2bf(f.y); u.s[2] = f2bf(f.z); u.s[3] = f2bf(f.w);
        ((int2*)Xb)[i] = u.v;
        return;
    }
    const int wb = bid - 8192;            // 0..255
    const int w = wb >> 6, r = wb & 63;
    const int n0 = (r >> 3) * 64, k0 = (r & 7) * 64;
    const float* W = (w == 0) ? W0 : (w == 1) ? W1 : (w == 2) ? W2 : W3;
#pragma unroll
    for (int rr = 0; rr < 4; ++rr) {
        int c = rr * 256 + tid;           // 0..1023 float4-chunks
        int row = c >> 4, col4 = (c & 15) * 4;
        float4 f = *(const float4*)&W[(size_t)(k0 + row) * 512 + n0 + col4];
        sT[col4 + 0][row] = f2bf(f.x);
        sT[col4 + 1][row] = f2bf(f.y);
        sT[col4 + 2][row] = f2bf(f.z);
        sT[col4 + 3][row] = f2bf(f.w);
    }
    __syncthreads();
#pragma unroll
    for (int rr = 0; rr < 2; ++rr) {
        int c = rr * 256 + tid;           // 0..511 int4-chunks
        int f = c >> 3, k8 = (c & 7) * 8;
        int4 v = *(const int4*)&sT[f][k8];
        *(int4*)&W4T[(size_t)w * 262144 + (size_t)(n0 + f) * 512 + k0 + k8] = v;
    }
}

// ---------------- 128x128 MFMA core: double-buffered, ONE barrier per K-step ----------------
// sA,sB: each 2 panels of [128][32] (8192 shorts). Prefetch for step k+1 issued
// right after the barrier; MFMA on step k overlaps the in-flight loads; next
// barrier drains loads that had a full compute phase to land.

#define LDS_DBUF __shared__ short sA[8192], sB[8192]

__device__ inline void mfma_kloop_dbuf(const short* __restrict__ A, int lda,
                                       const short* __restrict__ B, int ldb,
                                       int Kd, f32x4* acc,
                                       short* sA, short* sB) {
    const int tid = threadIdx.x, lane = tid & 63, wv = tid >> 6;
    const int quad = lane >> 4, lr = lane & 15;
    const int wr = (wv >> 1) * 64, wc = (wv & 1) * 64;
    const int c0 = tid, c1 = tid + 256;
    const int r0 = c0 >> 2, k80 = (c0 & 3) * 8;
    const int r1 = c1 >> 2, k81 = (c1 & 3) * 8;

    __syncthreads();   // protect buffers from a previous call's readers
    cp16_async(A + (size_t)r0 * lda + k80, sA + c0 * 8);
    cp16_async(A + (size_t)r1 * lda + k81, sA + c1 * 8);
    cp16_async(B + (size_t)r0 * ldb + k80, sB + c0 * 8);
    cp16_async(B + (size_t)r1 * ldb + k81, sB + c1 * 8);

    int cur = 0;
    for (int k0 = 0; k0 < Kd; k0 += 32) {
        __syncthreads();   // drains prefetch into cur; nxt's readers finished last iter
        const int nxt = cur ^ 1;
        if (k0 + 32 < Kd) {
            const short* An = A + k0 + 32;
            const short* Bn = B + k0 + 32;
            cp16_async(An + (size_t)r0 * lda + k80, sA + nxt * 4096 + c0 * 8);
            cp16_async(An + (size_t)r1 * lda + k81, sA + nxt * 4096 + c1 * 8);
            cp16_async(Bn + (size_t)r0 * ldb + k80, sB + nxt * 4096 + c0 * 8);
            cp16_async(Bn + (size_t)r1 * ldb + k81, sB + nxt * 4096 + c1 * 8);
        }
        const short* pa = sA + cur * 4096;
        const short* pb = sB + cur * 4096;
        bf16x8 af[4], bfr[4];
#pragma unroll
        for (int i = 0; i < 4; ++i)
            af[i] = *(const bf16x8*)&pa[(wr + i * 16 + lr) * 32 + quad * 8];
#pragma unroll
        for (int j = 0; j < 4; ++j)
            bfr[j] = *(const bf16x8*)&pb[(wc + j * 16 + lr) * 32 + quad * 8];
#pragma unroll
        for (int i = 0; i < 4; ++i)
#pragma unroll
            for (int j = 0; j < 4; ++j)
                acc[i * 4 + j] = __builtin_amdgcn_mfma_f32_16x16x32_bf16(af[i], bfr[j], acc[i * 4 + j], 0, 0, 0);
        cur = nxt;
    }
}

__device__ inline void store_out(float* p, float v) { *p = v; }
__device__ inline void store_out(short* p, float v) { *p = f2bf(v); }

template <typename OutT>
__device__ inline void store_tile128(OutT* C, int ldc, const f32x4* acc) {
    const int lane = threadIdx.x & 63, wv = threadIdx.x >> 6;
    const int quad = lane >> 4, lr = lane & 15;
    const int wr = (wv >> 1) * 64, wc = (wv & 1) * 64;
#pragma unroll
    for (int i = 0; i < 4; ++i)
#pragma unroll
        for (int j = 0; j < 4; ++j)
#pragma unroll
            for (int r = 0; r < 4; ++r)
                store_out(&C[(size_t)(wr + i * 16 + quad * 4 + r) * ldc + wc + j * 16 + lr],
                          acc[i * 4 + j][r]);
}

// ---------------- unified projections (narrow, 1536 blocks) ----------------
__global__ __launch_bounds__(256, 2) void proj_all(const short* __restrict__ Xb,
                                                   const short* __restrict__ W4T,
                                                   short* __restrict__ Qb, short* __restrict__ Kb,
                                                   short* __restrict__ Vt, short* __restrict__ Kt) {
    LDS_DBUF;
    f32x4 acc[16];
#pragma unroll
    for (int i = 0; i < 16; ++i) acc[i] = (f32x4){0.f, 0.f, 0.f, 0.f};
    const int bid = blockIdx.x;
    const int lane = threadIdx.x & 63, wv = threadIdx.x >> 6;
    const int quad = lane >> 4, lr = lane & 15;
    const int wr = (wv >> 1) * 64, wc = (wv & 1) * 64;
    if (bid < 1024) {
        const int mt = bid >> 3, by = bid & 7;
        const short* At = Xb + (size_t)mt * 128 * 512;
        const short* Bt = W4T + (size_t)by * 128 * 512;   // by<4: Wq cols, else Wk cols
        short* Ct = ((by < 4) ? Qb : Kb) + (size_t)mt * 128 * 512 + (by & 3) * 128;
        mfma_kloop_dbuf(At, 512, Bt, 512, 512, acc, sA, sB);
        store_tile128(Ct, 512, acc);
        if (by >= 4) {   // emit Kt[b][f][t] from registers
            const int b = mt >> 5;
            const int t0b = (mt & 31) * 128;
            const int f0 = (by - 4) * 128;
#pragma unroll
            for (int i = 0; i < 4; ++i)
#pragma unroll
                for (int j = 0; j < 4; ++j) {
                    int f = f0 + wc + j * 16 + lr;
                    int tt0 = t0b + wr + i * 16 + quad * 4;
                    short tmp[4];
#pragma unroll
                    for (int r = 0; r < 4; ++r) tmp[r] = f2bf(acc[i * 4 + j][r]);
                    *(int2*)&Kt[((size_t)b * 512 + f) * 4096 + tt0] = *(const int2*)tmp;
                }
        }
    } else {
        const int r = bid - 1024;
        const int b = r & 3, tt = (r >> 2) & 31, ft = r >> 7;
        const short* At = W4T + (size_t)2 * 262144 + (size_t)ft * 128 * 512;   // Wv
        const short* Bt = Xb + ((size_t)b * 4096 + tt * 128) * 512;
        short* Ct = Vt + (size_t)b * 512 * 4096 + (size_t)ft * 128 * 4096 + tt * 128;
        mfma_kloop_dbuf(At, 512, Bt, 512, 512, acc, sA, sB);
        store_tile128(Ct, 4096, acc);
    }
}

// ---------------- phaseA: AM[b,c][v][k] = V_c^T K_c (1024 blocks) ----------------
__global__ __launch_bounds__(256, 2) void phaseA_k(const short* __restrict__ Vt,
                                                   const short* __restrict__ Kt,
                                                   short* __restrict__ AM) {
    LDS_DBUF;
    const int vb = blockIdx.x;
    const int xt = vb & 3, yt = (vb >> 2) & 3, bc = vb >> 4;
    const int b = bc >> 4, c = bc & 15;
    const short* Ap = Vt + ((size_t)b * 512 + xt * 128) * 4096 + c * 256;
    const short* Bp = Kt + ((size_t)b * 512 + yt * 128) * 4096 + c * 256;
    short* Cp = AM + (size_t)bc * 262144 + (size_t)xt * 128 * 512 + yt * 128;
    f32x4 acc[16];
#pragma unroll
    for (int i = 0; i < 16; ++i) acc[i] = (f32x4){0.f, 0.f, 0.f, 0.f};
    mfma_kloop_dbuf(Ap, 4096, Bp, 4096, 256, acc, sA, sB);
    store_tile128(Cp, 512, acc);
}

// ---------------- scan (mem-bound) + phaseS (compute-bound), one launch ----------------
__global__ __launch_bounds__(256, 2) void scan_phaseS_k(short* __restrict__ AM,
                                                        const short* __restrict__ Q,
                                                        const short* __restrict__ K,
                                                        short* __restrict__ P) {
    LDS_DBUF;
    const int tid = threadIdx.x;
    if (blockIdx.x < 512) {
        int i = blockIdx.x * 256 + tid;   // 0..131071
        int b = i >> 15;
        int vk8 = i & 32767;
        size_t base = (size_t)b * 16 * 262144 + (size_t)vk8 * 8;
        float acc[8];
#pragma unroll
        for (int s = 0; s < 8; ++s) acc[s] = 0.f;
        for (int c = 0; c < 16; ++c) {
            short* p = AM + base + (size_t)c * 262144;
            short in8[8];
            *(int4*)in8 = *(const int4*)p;
            short out8[8];
#pragma unroll
            for (int s = 0; s < 8; ++s) out8[s] = f2bf(acc[s]);
            *(int4*)p = *(const int4*)out8;
#pragma unroll
            for (int s = 0; s < 8; ++s) acc[s] += bf2f(in8[s]);
        }
        return;
    }
    const int e = blockIdx.x - 512;       // 0..255
    const int bc = e >> 2, mt = e & 1, nt = (e >> 1) & 1;
    if (mt < nt) return;                  // dead tile (never read)
    const int b = bc >> 4, c = bc & 15;
    short* Pt = P + (size_t)bc * 65536 + (size_t)mt * 128 * 256 + nt * 128;
    const short* Ap = Q + ((size_t)(b * 4096 + c * 256 + mt * 128)) * 512;
    const short* Bp = K + ((size_t)(b * 4096 + c * 256 + nt * 128)) * 512;
    f32x4 acc[16];
#pragma unroll
    for (int i = 0; i < 16; ++i) acc[i] = (f32x4){0.f, 0.f, 0.f, 0.f};
    mfma_kloop_dbuf(Ap, 512, Bp, 512, 512, acc, sA, sB);
    const int lane = tid & 63, wv = tid >> 6;
    const int quad = lane >> 4, lr = lane & 15;
    const int wr = (wv >> 1) * 64, wc = (wv & 1) * 64;
    const bool diag = (mt == nt);
#pragma unroll
    for (int i = 0; i < 4; ++i)
#pragma unroll
        for (int j = 0; j < 4; ++j)
#pragma unroll
            for (int r = 0; r < 4; ++r) {
                int t = wr + i * 16 + quad * 4 + r;
                int jj = wc + j * 16 + lr;
                float v = (!diag || jj <= t) ? acc[i * 4 + j][r] : 0.f;
                Pt[(size_t)t * 256 + jj] = f2bf(v);
            }
}

// ---------------- phaseY: Y_c = Q_c Mpre_c^T + tril(P_c) V_c (512 blocks) ----------------
__global__ __launch_bounds__(256, 2) void phaseY_k(const short* __restrict__ Q,
                                                   const short* __restrict__ Mpre,
                                                   const short* __restrict__ P,
                                                   const short* __restrict__ Vt,
                                                   short* __restrict__ Y) {
    LDS_DBUF;
    const int vb = blockIdx.x;
    const int mt = vb & 1, nt = (vb >> 1) & 3, bc = vb >> 3;
    const int b = bc >> 4, c = bc & 15;
    f32x4 acc[16];
#pragma unroll
    for (int i = 0; i < 16; ++i) acc[i] = (f32x4){0.f, 0.f, 0.f, 0.f};
    const short* Ai = Q + ((size_t)(b * 4096 + c * 256 + mt * 128)) * 512;
    const short* Bi = Mpre + (size_t)bc * 262144 + (size_t)nt * 128 * 512;
    mfma_kloop_dbuf(Ai, 512, Bi, 512, 512, acc, sA, sB);
    const short* Ap = P + (size_t)bc * 65536 + (size_t)mt * 128 * 256;
    const short* Bv = Vt + ((size_t)b * 512 + nt * 128) * 4096 + c * 256;
    mfma_kloop_dbuf(Ap, 256, Bv, 4096, (mt + 1) * 128, acc, sA, sB);
    short* Cp = Y + ((size_t)(b * 4096 + c * 256 + mt * 128)) * 512 + nt * 128;
    store_tile128(Cp, 512, acc);
}

// ---------------- output projection (512 blocks) ----------------
__global__ __launch_bounds__(256, 2) void outproj_k(const short* __restrict__ Y,
                                                    const short* __restrict__ W4T,
                                                    float* __restrict__ out) {
    LDS_DBUF;
    const int mt = blockIdx.x >> 2, nt = blockIdx.x & 3;
    const short* At = Y + (size_t)mt * 128 * 512;
    const short* Bt = W4T + (size_t)3 * 262144 + (size_t)nt * 128 * 512;   // Wo
    float* Ct = out + (size_t)mt * 128 * 512 + nt * 128;
    f32x4 acc[16];
#pragma unroll
    for (int i = 0; i < 16; ++i) acc[i] = (f32x4){0.f, 0.f, 0.f, 0.f};
    mfma_kloop_dbuf(At, 512, Bt, 512, 512, acc, sA, sB);
    store_tile128(Ct, 512, acc);
}

// ---------------- host ----------------

extern "C" void kernel_launch(void* const* d_in, const int* in_sizes, int n_in,
                              void* d_out, int out_size, void* d_ws, size_t ws_size,
                              hipStream_t stream) {
    const float* x  = (const float*)d_in[0];
    const float* Wq = (const float*)d_in[1];
    const float* Wk = (const float*)d_in[2];
    const float* Wv = (const float*)d_in[3];
    const float* Wo = (const float*)d_in[4];
    float* out = (float*)d_out;

    const size_t NTD = 16384 * 512;   // 8,388,608 elems

    short* ws  = (short*)d_ws;
    short* Xb  = ws;                  // 8.39M
    short* Qb  = Xb + NTD;
    short* Kb  = Qb + NTD;
    short* Kt  = Kb + NTD;
    short* Vt  = Kt + NTD;
    short* P   = Vt + NTD;            // 4.19M
    short* W4T = P + 4194304;         // 1.05M : WqT|WkT|WvT|WoT
    short* AM  = W4T + 1048576;       // 16.78M
    short* Yb  = Kb;                  // Kb dead after scan_phaseS

    prep_kernel<<<8448, 256, 0, stream>>>(x, Xb, Wq, Wk, Wv, Wo, W4T);
    proj_all<<<1536, 256, 0, stream>>>(Xb, W4T, Qb, Kb, Vt, Kt);
    phaseA_k<<<1024, 256, 0, stream>>>(Vt, Kt, AM);
    scan_phaseS_k<<<768, 256, 0, stream>>>(AM, Qb, Kb, P);
    phaseY_k<<<512, 256, 0, stream>>>(Qb, AM, P, Vt, Yb);
    outproj_k<<<512, 256, 0, stream>>>(Yb, W4T, out);
}